// Round 1
// baseline (278.466 us; speedup 1.0000x reference)
//
#include <hip/hip_runtime.h>

// Problem constants (from reference): B=16, C=8, H=W=512, N=16384
constexpr int kN      = 16384;
constexpr int kNTOT   = 16 * 8 * 16384;   // intervals per set = 2,097,152
// plane stride = H*W = 262144 = 1<<18 ; row stride = 512 = 1<<9 ; N = 1<<14

__device__ __forceinline__ double wave_reduce_sum(double x) {
#pragma unroll
    for (int o = 32; o > 0; o >>= 1) x += __shfl_down(x, o, 64);
    return x;
}

__global__ __launch_bounds__(256) void bd_partial_kernel(
        const float* __restrict__ pred,
        const int*   __restrict__ iv0,
        const int*   __restrict__ iv1,
        double*      __restrict__ partials) {
    const int tid    = blockIdx.x * blockDim.x + threadIdx.x;
    const int stride = gridDim.x * blockDim.x;

    double acc = 0.0;
    for (int i = tid; i < kNTOT; i += stride) {
        const int bc = i >> 14;                        // i / N  -> which (b,c) plane
        const float* plane = pred + ((size_t)bc << 18); // bc * H*W

        // 4 contiguous int32 indices per interval: (r0,c0,r1,c1) — 16B coalesced
        const int4 a = *reinterpret_cast<const int4*>(iv0 + 4ll * i);
        const float d0 = plane[(a.x << 9) + a.y] - plane[(a.z << 9) + a.w];

        const int4 b = *reinterpret_cast<const int4*>(iv1 + 4ll * i);
        const float d1 = plane[(b.x << 9) + b.y] - plane[(b.z << 9) + b.w];

        acc += (double)d0 * (double)d0 + (double)d1 * (double)d1;
    }

    acc = wave_reduce_sum(acc);
    __shared__ double s[4];
    const int lane = threadIdx.x & 63;
    const int wid  = threadIdx.x >> 6;
    if (lane == 0) s[wid] = acc;
    __syncthreads();
    if (threadIdx.x == 0) {
        partials[blockIdx.x] = s[0] + s[1] + s[2] + s[3];
    }
}

__global__ __launch_bounds__(256) void bd_final_kernel(
        const double* __restrict__ partials, int n, float* __restrict__ out) {
    double acc = 0.0;
    for (int i = threadIdx.x; i < n; i += 256) acc += partials[i];
    acc = wave_reduce_sum(acc);
    __shared__ double s[4];
    const int lane = threadIdx.x & 63;
    const int wid  = threadIdx.x >> 6;
    if (lane == 0) s[wid] = acc;
    __syncthreads();
    if (threadIdx.x == 0) {
        // loss = (sum0 + sum1) / B , B = 16
        out[0] = (float)((s[0] + s[1] + s[2] + s[3]) * (1.0 / 16.0));
    }
}

extern "C" void kernel_launch(void* const* d_in, const int* in_sizes, int n_in,
                              void* d_out, int out_size, void* d_ws, size_t ws_size,
                              hipStream_t stream) {
    const float* pred = (const float*)d_in[0];
    const int*   iv0  = (const int*)d_in[1];
    const int*   iv1  = (const int*)d_in[2];
    float*  out      = (float*)d_out;
    double* partials = (double*)d_ws;   // 2048 doubles = 16 KiB scratch

    constexpr int kBlocks = 2048;
    bd_partial_kernel<<<kBlocks, 256, 0, stream>>>(pred, iv0, iv1, partials);
    bd_final_kernel<<<1, 256, 0, stream>>>(partials, kBlocks, out);
}

// Round 4
// 270.540 us; speedup vs baseline: 1.0293x; 1.0293x over previous
//
#include <hip/hip_runtime.h>

// Problem: B=16, C=8, H=W=512, N=16384
// plane stride H*W = 1<<18 floats; row stride = 1<<9; N = 1<<14
// items per set = 16*8*16384 = 2,097,152 ; each item does both sets (8 gathers)

constexpr int kXcds          = 8;
constexpr int kPlanes        = 16 * 8;              // 128 (b,c) planes
constexpr int kPlanesPerXcd  = kPlanes / kXcds;     // 16
constexpr int kItemsPerXcd   = kPlanesPerXcd << 14; // 262144
constexpr int kBlocksPerXcd  = 128;
constexpr int kBlocks        = kBlocksPerXcd * kXcds;   // 1024
constexpr int kThreadsPerXcd = kBlocksPerXcd * 256;     // 32768
constexpr int kIters         = kItemsPerXcd / kThreadsPerXcd; // 8

__device__ __forceinline__ double wave_reduce_sum(double x) {
#pragma unroll
    for (int o = 32; o > 0; o >>= 1) x += __shfl_down(x, o, 64);
    return x;
}

__global__ __launch_bounds__(256) void bd_partial_kernel(
        const float* __restrict__ pred,
        const int*   __restrict__ iv0,
        const int*   __restrict__ iv1,
        double*      __restrict__ partials) {
    // XCD-partitioned schedule: blocks with the same (blockIdx.x & 7) land on
    // the same XCD (round-robin dispatch); each XCD owns 16 contiguous planes
    // so its gathers stay inside ~2 MiB at a time -> private-L2 resident.
    const int xcd  = blockIdx.x & 7;
    const int tloc = (blockIdx.x >> 3) * 256 + threadIdx.x;   // 0..32767 within XCD
    const int ibase = xcd * kItemsPerXcd;

    double acc = 0.0;
#pragma unroll 2
    for (int it = 0; it < kIters; ++it) {
        const int i  = ibase + it * kThreadsPerXcd + tloc;
        const int bc = i >> 14;
        const float* plane = pred + ((size_t)bc << 18);

        const int4 a = *reinterpret_cast<const int4*>(iv0 + 4ll * i);
        const int4 b = *reinterpret_cast<const int4*>(iv1 + 4ll * i);

        const float d0 = plane[(a.x << 9) + a.y] - plane[(a.z << 9) + a.w];
        const float d1 = plane[(b.x << 9) + b.y] - plane[(b.z << 9) + b.w];

        acc += (double)d0 * (double)d0 + (double)d1 * (double)d1;
    }

    acc = wave_reduce_sum(acc);
    __shared__ double s[4];
    const int lane = threadIdx.x & 63;
    const int wid  = threadIdx.x >> 6;
    if (lane == 0) s[wid] = acc;
    __syncthreads();
    if (threadIdx.x == 0) partials[blockIdx.x] = s[0] + s[1] + s[2] + s[3];
}

__global__ __launch_bounds__(256) void bd_final_kernel(
        const double* __restrict__ partials, int n, float* __restrict__ out) {
    double acc = 0.0;
    for (int i = threadIdx.x; i < n; i += 256) acc += partials[i];
    acc = wave_reduce_sum(acc);
    __shared__ double s[4];
    const int lane = threadIdx.x & 63;
    const int wid  = threadIdx.x >> 6;
    if (lane == 0) s[wid] = acc;
    __syncthreads();
    if (threadIdx.x == 0)
        out[0] = (float)((s[0] + s[1] + s[2] + s[3]) * (1.0 / 16.0));  // /B, B=16
}

extern "C" void kernel_launch(void* const* d_in, const int* in_sizes, int n_in,
                              void* d_out, int out_size, void* d_ws, size_t ws_size,
                              hipStream_t stream) {
    const float* pred = (const float*)d_in[0];
    const int*   iv0  = (const int*)d_in[1];
    const int*   iv1  = (const int*)d_in[2];
    float*  out      = (float*)d_out;
    double* partials = (double*)d_ws;   // 1024 doubles = 8 KiB scratch

    bd_partial_kernel<<<kBlocks, 256, 0, stream>>>(pred, iv0, iv1, partials);
    bd_final_kernel<<<1, 256, 0, stream>>>(partials, kBlocks, out);
}

// Round 9
// 259.187 us; speedup vs baseline: 1.0744x; 1.0438x over previous
//
#include <hip/hip_runtime.h>

// Problem: B=16, C=8, H=W=512, N=16384
// plane stride H*W = 1<<18 floats; row stride = 1<<9; N = 1<<14
// items per set = 2,097,152 ; each item reads 4 idx ints per set + 4 gathers total/set-pair

typedef int int4v __attribute__((ext_vector_type(4)));

constexpr int kXcds          = 8;
constexpr int kPlanesPerXcd  = 16;                  // 128 planes / 8 XCDs
constexpr int kItemsPerXcd   = kPlanesPerXcd << 14; // 262144
constexpr int kBlocksPerXcd  = 256;                 // R4 was 128 -> 2x waves/CU
constexpr int kBlocks        = kBlocksPerXcd * kXcds;     // 2048 (8 blocks/CU)
constexpr int kThreadsPerXcd = kBlocksPerXcd * 256;       // 65536
constexpr int kIters         = kItemsPerXcd / kThreadsPerXcd; // 4

__device__ __forceinline__ double wave_reduce_sum(double x) {
#pragma unroll
    for (int o = 32; o > 0; o >>= 1) x += __shfl_down(x, o, 64);
    return x;
}

__global__ __launch_bounds__(256) void bd_partial_kernel(
        const float* __restrict__ pred,
        const int*   __restrict__ iv0,
        const int*   __restrict__ iv1,
        double*      __restrict__ partials) {
    // XCD-partitioned: blockIdx.x & 7 selects the XCD (round-robin dispatch);
    // each XCD owns 16 contiguous planes. Strided sweeps keep the instantaneous
    // gather window small (sweep = 4 planes; pipeline depth 2 -> ~8 planes,
    // overflow lands in L3 not HBM since prediction fits L3 entirely).
    const int xcd   = blockIdx.x & 7;
    const int tloc  = (blockIdx.x >> 3) * 256 + threadIdx.x;   // 0..65535 in XCD
    const int ibase = xcd * kItemsPerXcd;

    const int4v* q0 = reinterpret_cast<const int4v*>(iv0);
    const int4v* q1 = reinterpret_cast<const int4v*>(iv1);

    int   i = ibase + tloc;
    // nontemporal: idx data is stream-once; keep it out of L2 so the 4 MiB
    // per-XCD L2 stays dedicated to the prediction plane window.
    int4v a = __builtin_nontemporal_load(q0 + i);
    int4v b = __builtin_nontemporal_load(q1 + i);

    double acc = 0.0;
#pragma unroll
    for (int it = 0; it < kIters; ++it) {
        const float* plane = pred + ((size_t)(i >> 14) << 18);

        // 4 independent divergent gathers in flight per wave
        const float birth0 = plane[(a.x << 9) + a.y];
        const float death0 = plane[(a.z << 9) + a.w];
        const float birth1 = plane[(b.x << 9) + b.y];
        const float death1 = plane[(b.z << 9) + b.w];

        if (it + 1 < kIters) {           // prefetch next iteration's indices
            i += kThreadsPerXcd;
            a = __builtin_nontemporal_load(q0 + i);
            b = __builtin_nontemporal_load(q1 + i);
        }

        const float d0 = birth0 - death0;
        const float d1 = birth1 - death1;
        acc += (double)d0 * (double)d0 + (double)d1 * (double)d1;
    }

    acc = wave_reduce_sum(acc);
    __shared__ double s[4];
    const int lane = threadIdx.x & 63;
    const int wid  = threadIdx.x >> 6;
    if (lane == 0) s[wid] = acc;
    __syncthreads();
    if (threadIdx.x == 0) partials[blockIdx.x] = s[0] + s[1] + s[2] + s[3];
}

__global__ __launch_bounds__(256) void bd_final_kernel(
        const double* __restrict__ partials, int n, float* __restrict__ out) {
    double acc = 0.0;
    for (int i = threadIdx.x; i < n; i += 256) acc += partials[i];
    acc = wave_reduce_sum(acc);
    __shared__ double s[4];
    const int lane = threadIdx.x & 63;
    const int wid  = threadIdx.x >> 6;
    if (lane == 0) s[wid] = acc;
    __syncthreads();
    if (threadIdx.x == 0)
        out[0] = (float)((s[0] + s[1] + s[2] + s[3]) * (1.0 / 16.0));  // /B, B=16
}

extern "C" void kernel_launch(void* const* d_in, const int* in_sizes, int n_in,
                              void* d_out, int out_size, void* d_ws, size_t ws_size,
                              hipStream_t stream) {
    const float* pred = (const float*)d_in[0];
    const int*   iv0  = (const int*)d_in[1];
    const int*   iv1  = (const int*)d_in[2];
    float*  out      = (float*)d_out;
    double* partials = (double*)d_ws;   // 2048 doubles = 16 KiB scratch

    bd_partial_kernel<<<kBlocks, 256, 0, stream>>>(pred, iv0, iv1, partials);
    bd_final_kernel<<<1, 256, 0, stream>>>(partials, kBlocks, out);
}